// Round 1
// baseline (24531.799 us; speedup 1.0000x reference)
//
#include <hip/hip_runtime.h>
#include <math.h>

#define HID    512
#define NIN    256
#define TIN    4096
#define TSAVE  1024
#define NSTEP  1023
#define NEVAL  (NSTEP*4)
#define NWG    16
#define SLICE  32          // state elements owned per WG
#define NTHREADS 256

// searchsorted(linspace(0,1,4096), t, side='left') clipped to [0, 4095]
__device__ __forceinline__ int zoh_index(float t) {
  const float delta = 1.0f / 4095.0f;
  int lo = 0, hi = TIN;
  while (lo < hi) {
    int mid = (lo + hi) >> 1;
    float g = (float)mid * delta;
    if (g < t) lo = mid + 1; else hi = mid;
  }
  return lo > TIN - 1 ? TIN - 1 : lo;
}

// Precompute gu[e][0:512]  = U_tau @ I(t_e) + b_tau
//            gu[e][512:1024] = U_f  @ I(t_e) + b_f      for all 4092 eval times.
__global__ void __launch_bounds__(256)
gu_kernel(const float* __restrict__ I_seq, const float* __restrict__ t_save,
          const float* __restrict__ U_tau, const float* __restrict__ b_tau,
          const float* __restrict__ U_f,   const float* __restrict__ b_f,
          float* __restrict__ gu)
{
  __shared__ float Ish[NIN];
  const int e = blockIdx.x;
  const int tid = threadIdx.x;
  const int n = e >> 2, s = e & 3;
  const float t0 = t_save[n], t1 = t_save[n + 1];
  const float dt = t1 - t0;
  const float third = 1.0f / 3.0f;
  float t;
  if      (s == 0) t = t0;
  else if (s == 1) t = t0 + dt * third;
  else if (s == 2) t = t0 + (dt * 2.0f) * third;
  else             t = t1;
  const int idx = zoh_index(t);
  Ish[tid] = I_seq[idx * NIN + tid];
  __syncthreads();
  float* go = gu + (size_t)e * 1024;
  #pragma unroll
  for (int m = 0; m < 2; ++m) {
    const float* __restrict__ U = m ? U_f : U_tau;
    const float* __restrict__ b = m ? b_f : b_tau;
    #pragma unroll
    for (int hh = 0; hh < 2; ++hh) {
      const int h = tid + hh * 256;
      const float4* __restrict__ Ur = (const float4*)(U + (size_t)h * NIN);
      float acc = 0.f;
      #pragma unroll 8
      for (int k = 0; k < NIN / 4; ++k) {
        float4 u = Ur[k];
        acc = fmaf(u.x, Ish[4*k+0], acc);
        acc = fmaf(u.y, Ish[4*k+1], acc);
        acc = fmaf(u.z, Ish[4*k+2], acc);
        acc = fmaf(u.w, Ish[4*k+3], acc);
      }
      go[m * 512 + h] = acc + b[h];
    }
  }
}

// Persistent cooperative scan kernel. 16 WGs x 256 threads.
// WG w owns state slice [32w, 32w+32). Thread (r=tid>>2, seg=tid&3) holds
// W row (tau rows r<32, f rows r>=32), columns [seg*128, seg*128+128) in VGPRs.
__global__ void __launch_bounds__(NTHREADS, 1)
ltc_main(const float* __restrict__ x0, const float* __restrict__ t_save,
         const float* __restrict__ W_tau, const float* __restrict__ tau0,
         const float* __restrict__ W_f,
         const float* __restrict__ gu,
         float* __restrict__ xbuf,
         unsigned* __restrict__ bar,
         float* __restrict__ out)
{
  const int wg   = blockIdx.x;
  const int tid  = threadIdx.x;
  const int r    = tid >> 2;
  const int seg  = tid & 3;
  const int base = wg * SLICE;

  const float* wrow = (r < SLICE)
      ? (W_tau + (size_t)(base + r) * HID + seg * 128)
      : (W_f   + (size_t)(base + r - SLICE) * HID + seg * 128);

  float w[128];
  #pragma unroll
  for (int j = 0; j < 32; ++j) {
    float4 v = ((const float4*)wrow)[j];
    w[4*j+0] = v.x; w[4*j+1] = v.y; w[4*j+2] = v.z; w[4*j+3] = v.w;
  }

  __shared__ float pre[64];

  float y0 = 0.f, k1 = 0.f, k2 = 0.f, k3 = 0.f, curx = 0.f, tz = 0.f;
  if (tid < SLICE) {
    y0   = x0[base + tid];
    curx = y0;
    tz   = tau0[base + tid];
    out[base + tid] = y0;            // out[0] = x0
  }

  unsigned target = 0;

  for (int n = 0; n < NSTEP; ++n) {
    const float t0 = t_save[n], t1 = t_save[n + 1];
    const float dt = t1 - t0;
    #pragma unroll
    for (int s = 0; s < 4; ++s) {
      const int e = (n << 2) + s;

      // issue gu loads early (independent of x)
      float gt = 0.f, gf = 0.f;
      if (tid < SLICE) {
        const float* g = gu + (size_t)e * 1024 + base + tid;
        gt = g[0];
        gf = g[512];
      }

      // matvec: acc = sum_j W[row][seg*128+j] * x[seg*128+j]
      const float* xsrc = (e == 0) ? x0 : xbuf;
      const float4* xv = (const float4*)(xsrc + seg * 128);
      float acc = 0.f;
      #pragma unroll
      for (int j = 0; j < 32; ++j) {
        float4 v = xv[j];
        acc = fmaf(w[4*j+0], v.x, acc);
        acc = fmaf(w[4*j+1], v.y, acc);
        acc = fmaf(w[4*j+2], v.z, acc);
        acc = fmaf(w[4*j+3], v.w, acc);
      }
      acc += __shfl_xor(acc, 1);
      acc += __shfl_xor(acc, 2);
      if (seg == 0) pre[r] = acc;
      __syncthreads();

      // elementwise + RK4 state update on owned slice (wave 0, lanes 0..31)
      if (tid < SLICE) {
        const float zt  = pre[tid] + gt;
        const float zf  = pre[SLICE + tid] + gf;
        const float sp  = fmaxf(zt, 0.f) + log1pf(expf(-fabsf(zt)));
        const float tau = tz + sp;
        const float f   = tanhf(zf);
        const float d   = f - curx / tau;
        float xnew;
        if      (s == 0) { k1 = d; xnew = y0 + dt * k1 * (1.0f/3.0f); }
        else if (s == 1) { k2 = d; xnew = y0 + dt * (k2 - k1 * (1.0f/3.0f)); }
        else if (s == 2) { k3 = d; xnew = y0 + dt * (k1 - k2 + k3); }
        else {
          xnew = y0 + (k1 + 3.0f * (k2 + k3) + d) * dt * 0.125f;
          y0 = xnew;
          out[(size_t)(n + 1) * HID + base + tid] = xnew;
        }
        curx = xnew;
        xbuf[base + tid] = xnew;
      }

      // grid barrier (device-scope): monotonically increasing counter
      if (tid == 0) {
        __threadfence();                       // release xbuf writes
        atomicAdd(bar, 1u);
        target += NWG;
        while (__hip_atomic_load(bar, __ATOMIC_RELAXED, __HIP_MEMORY_SCOPE_AGENT) < target) { }
        __threadfence();                       // acquire others' xbuf writes
      }
      __syncthreads();
    }
  }
}

extern "C" void kernel_launch(void* const* d_in, const int* in_sizes, int n_in,
                              void* d_out, int out_size, void* d_ws, size_t ws_size,
                              hipStream_t stream) {
  const float* x0     = (const float*)d_in[0];
  const float* I_seq  = (const float*)d_in[1];
  const float* t_save = (const float*)d_in[2];
  const float* W_tau  = (const float*)d_in[3];
  const float* U_tau  = (const float*)d_in[4];
  const float* b_tau  = (const float*)d_in[5];
  const float* tau0   = (const float*)d_in[6];
  const float* W_f    = (const float*)d_in[7];
  const float* U_f    = (const float*)d_in[8];
  const float* b_f    = (const float*)d_in[9];
  float* out = (float*)d_out;

  char* ws = (char*)d_ws;
  unsigned* bar = (unsigned*)ws;               // [0,256): barrier counter
  float* xbuf   = (float*)(ws + 256);          // [256, 256+2KB): x exchange buffer
  float* gu     = (float*)(ws + 4096);         // NEVAL * 1024 floats (~16.8 MB)

  hipMemsetAsync(bar, 0, 256, stream);
  gu_kernel<<<NEVAL, 256, 0, stream>>>(I_seq, t_save, U_tau, b_tau, U_f, b_f, gu);

  void* args[] = { (void*)&x0, (void*)&t_save, (void*)&W_tau, (void*)&tau0, (void*)&W_f,
                   (void*)&gu, (void*)&xbuf, (void*)&bar, (void*)&out };
  hipLaunchCooperativeKernel((const void*)ltc_main, dim3(NWG), dim3(NTHREADS),
                             args, 0, stream);
}

// Round 2
// 9282.117 us; speedup vs baseline: 2.6429x; 2.6429x over previous
//
#include <hip/hip_runtime.h>
#include <math.h>

#define HID    512
#define NIN    256
#define TIN    4096
#define NSTEP  1023
#define NEVAL  (NSTEP*4)
#define NWG    16
#define SLICE  32          // state elements owned per WG
#define NTH    1024

// searchsorted(linspace(0,1,4096), t, side='left') clipped to [0, 4095]
__device__ __forceinline__ int zoh_index(float t) {
  const float delta = 1.0f / 4095.0f;
  int lo = 0, hi = TIN;
  while (lo < hi) {
    int mid = (lo + hi) >> 1;
    float g = (float)mid * delta;
    if (g < t) lo = mid + 1; else hi = mid;
  }
  return lo > TIN - 1 ? TIN - 1 : lo;
}

// Precompute gu[e][0:512]   = U_tau @ I(t_e) + b_tau
//            gu[e][512:1024] = U_f  @ I(t_e) + b_f     for all 4092 eval times.
__global__ void __launch_bounds__(256)
gu_kernel(const float* __restrict__ I_seq, const float* __restrict__ t_save,
          const float* __restrict__ U_tau, const float* __restrict__ b_tau,
          const float* __restrict__ U_f,   const float* __restrict__ b_f,
          float* __restrict__ gu)
{
  __shared__ float Ish[NIN];
  const int e = blockIdx.x;
  const int tid = threadIdx.x;
  const int n = e >> 2, s = e & 3;
  const float t0 = t_save[n], t1 = t_save[n + 1];
  const float dt = t1 - t0;
  const float third = 1.0f / 3.0f;
  float t;
  if      (s == 0) t = t0;
  else if (s == 1) t = t0 + dt * third;
  else if (s == 2) t = t0 + (dt * 2.0f) * third;
  else             t = t1;
  const int idx = zoh_index(t);
  Ish[tid] = I_seq[idx * NIN + tid];
  __syncthreads();
  float* go = gu + (size_t)e * 1024;
  #pragma unroll
  for (int m = 0; m < 2; ++m) {
    const float* __restrict__ U = m ? U_f : U_tau;
    const float* __restrict__ b = m ? b_f : b_tau;
    #pragma unroll
    for (int hh = 0; hh < 2; ++hh) {
      const int h = tid + hh * 256;
      const float4* __restrict__ Ur = (const float4*)(U + (size_t)h * NIN);
      float acc = 0.f;
      #pragma unroll 8
      for (int k = 0; k < NIN / 4; ++k) {
        float4 u = Ur[k];
        acc = fmaf(u.x, Ish[4*k+0], acc);
        acc = fmaf(u.y, Ish[4*k+1], acc);
        acc = fmaf(u.z, Ish[4*k+2], acc);
        acc = fmaf(u.w, Ish[4*k+3], acc);
      }
      go[m * 512 + h] = acc + b[h];
    }
  }
}

// Persistent cooperative scan. 16 WGs x 1024 threads.
// WG w owns states [32w, 32w+32) -> 64 weight rows (32 tau + 32 f).
// Thread (row=tid>>4, seg=tid&15) holds 32 weights (8 float4) in VGPRs.
// Cross-WG exchange entirely via agent-scope relaxed atomics (coherent point),
// ordered by s_waitcnt vmcnt(0) -> NO L2 writeback/invalidate fences.
__global__ void __launch_bounds__(NTH, 4)
ltc_main(const float* __restrict__ x0, const float* __restrict__ t_save,
         const float* __restrict__ W_tau, const float* __restrict__ tau0,
         const float* __restrict__ W_f,
         const float* __restrict__ gu,
         float* buf0, float* buf1,
         unsigned* bar,
         float* __restrict__ out)
{
  const int wg   = blockIdx.x;
  const int tid  = threadIdx.x;
  const int row  = tid >> 4;    // 0..63
  const int seg  = tid & 15;    // 0..15, 32 columns each
  const int base = wg * SLICE;

  const float* wrow = ((row < SLICE)
      ? (W_tau + (size_t)(base + row) * HID)
      : (W_f   + (size_t)(base + row - SLICE) * HID)) + seg * 32;

  float4 w4[8];
  #pragma unroll
  for (int t = 0; t < 8; ++t) w4[t] = ((const float4*)wrow)[t];

  // x staged per 32-float sub-segment, padded to 36 words -> <=2-way bank conflicts
  __shared__ float xsp[16 * 36];
  __shared__ float pre[64];

  float y0 = 0.f, k1 = 0.f, k2 = 0.f, k3 = 0.f, curx = 0.f, tz = 0.f;
  if (tid < SLICE) {
    y0   = x0[base + tid];
    curx = y0;
    tz   = tau0[base + tid];
    out[base + tid] = y0;            // out[0] = x0
  }

  for (int n = 0; n < NSTEP; ++n) {
    const float t0 = t_save[n], t1 = t_save[n + 1];
    const float dt = t1 - t0;
    #pragma unroll
    for (int s = 0; s < 4; ++s) {
      const int e = (n << 2) + s;

      // ---- barrier wait: all WGs finished eval e-1 ----
      if (tid == 0) {
        const unsigned tgt = (unsigned)(NWG * e);
        while (__hip_atomic_load(bar, __ATOMIC_RELAXED, __HIP_MEMORY_SCOPE_AGENT) < tgt) {
          __builtin_amdgcn_s_sleep(1);
        }
      }
      __syncthreads();
      asm volatile("" ::: "memory");

      // ---- gu loads (cached; used late, latency hidden) ----
      float gt = 0.f, gf = 0.f;
      if (tid < SLICE) {
        const float* g = gu + (size_t)e * 1024 + base + tid;
        gt = g[0];
        gf = g[512];
      }

      // ---- stage x_e into LDS (coherent loads, bypass stale L1/L2) ----
      if (tid < HID) {
        const float* src = (e == 0) ? x0 : ((e & 1) ? buf1 : buf0);
        float v = __hip_atomic_load(src + tid, __ATOMIC_RELAXED, __HIP_MEMORY_SCOPE_AGENT);
        xsp[(tid >> 5) * 36 + (tid & 31)] = v;
      }
      __syncthreads();

      // ---- matvec: 32 MACs/thread from VGPR weights + LDS x ----
      float acc = 0.f;
      #pragma unroll
      for (int t = 0; t < 8; ++t) {
        const float4 xv = *reinterpret_cast<const float4*>(&xsp[seg * 36 + 4 * t]);
        acc = fmaf(w4[t].x, xv.x, acc);
        acc = fmaf(w4[t].y, xv.y, acc);
        acc = fmaf(w4[t].z, xv.z, acc);
        acc = fmaf(w4[t].w, xv.w, acc);
      }
      acc += __shfl_xor(acc, 1);
      acc += __shfl_xor(acc, 2);
      acc += __shfl_xor(acc, 4);
      acc += __shfl_xor(acc, 8);
      if ((tid & 15) == 0) pre[row] = acc;
      __syncthreads();

      // ---- elementwise + RK4 update + release (wave 0 only) ----
      if (tid < 64) {
        if (tid < SLICE) {
          const float zt  = pre[tid] + gt;
          const float zf  = pre[SLICE + tid] + gf;
          const float ez  = __expf(-fabsf(zt));
          const float sp  = fmaxf(zt, 0.f) + __logf(1.f + ez);
          const float tau = tz + sp;
          const float ef  = __expf(-2.f * fabsf(zf));
          const float th  = (1.f - ef) / (1.f + ef);
          const float f   = (zf >= 0.f) ? th : -th;
          const float d   = f - curx / tau;
          float xnew;
          if      (s == 0) { k1 = d; xnew = y0 + dt * k1 * (1.0f/3.0f); }
          else if (s == 1) { k2 = d; xnew = y0 + dt * (k2 - k1 * (1.0f/3.0f)); }
          else if (s == 2) { k3 = d; xnew = y0 + dt * (k1 - k2 + k3); }
          else {
            xnew = y0 + (k1 + 3.0f * (k2 + k3) + d) * dt * 0.125f;
            y0 = xnew;
            out[(size_t)(n + 1) * HID + base + tid] = xnew;
          }
          curx = xnew;
          float* dst = (((e + 1) & 1) ? buf1 : buf0) + base + tid;
          __hip_atomic_store(dst, xnew, __ATOMIC_RELAXED, __HIP_MEMORY_SCOPE_AGENT);
        }
        // order the coherent stores before the barrier increment (wave-uniform)
        asm volatile("s_waitcnt vmcnt(0)" ::: "memory");
        if (tid == 0)
          __hip_atomic_fetch_add(bar, 1u, __ATOMIC_RELAXED, __HIP_MEMORY_SCOPE_AGENT);
      }
    }
  }
}

extern "C" void kernel_launch(void* const* d_in, const int* in_sizes, int n_in,
                              void* d_out, int out_size, void* d_ws, size_t ws_size,
                              hipStream_t stream) {
  const float* x0     = (const float*)d_in[0];
  const float* I_seq  = (const float*)d_in[1];
  const float* t_save = (const float*)d_in[2];
  const float* W_tau  = (const float*)d_in[3];
  const float* U_tau  = (const float*)d_in[4];
  const float* b_tau  = (const float*)d_in[5];
  const float* tau0   = (const float*)d_in[6];
  const float* W_f    = (const float*)d_in[7];
  const float* U_f    = (const float*)d_in[8];
  const float* b_f    = (const float*)d_in[9];
  float* out = (float*)d_out;

  char* ws = (char*)d_ws;
  unsigned* bar = (unsigned*)ws;               // [0,256): barrier counter
  float* buf0   = (float*)(ws + 4096);         // x exchange, even parity
  float* buf1   = (float*)(ws + 8192);         // x exchange, odd parity
  float* gu     = (float*)(ws + 16384);        // NEVAL * 1024 floats (~16.8 MB)

  hipMemsetAsync(bar, 0, 256, stream);
  gu_kernel<<<NEVAL, 256, 0, stream>>>(I_seq, t_save, U_tau, b_tau, U_f, b_f, gu);

  void* args[] = { (void*)&x0, (void*)&t_save, (void*)&W_tau, (void*)&tau0, (void*)&W_f,
                   (void*)&gu, (void*)&buf0, (void*)&buf1, (void*)&bar, (void*)&out };
  hipLaunchCooperativeKernel((const void*)ltc_main, dim3(NWG), dim3(NTH),
                             args, 0, stream);
}

// Round 3
// 6269.921 us; speedup vs baseline: 3.9126x; 1.4804x over previous
//
#include <hip/hip_runtime.h>
#include <math.h>

#define HID    512
#define NIN    256
#define TIN    4096
#define NSTEP  1023
#define NEVAL  (NSTEP*4)
#define NWG    16
#define SLICE  32          // state elements owned per WG
#define NTH    1024

// searchsorted(linspace(0,1,4096), t, side='left') clipped to [0, 4095]
__device__ __forceinline__ int zoh_index(float t) {
  const float delta = 1.0f / 4095.0f;
  int lo = 0, hi = TIN;
  while (lo < hi) {
    int mid = (lo + hi) >> 1;
    float g = (float)mid * delta;
    if (g < t) lo = mid + 1; else hi = mid;
  }
  return lo > TIN - 1 ? TIN - 1 : lo;
}

// Precompute gu[e][0:512]   = U_tau @ I(t_e) + b_tau
//            gu[e][512:1024] = U_f  @ I(t_e) + b_f     for all 4092 eval times.
__global__ void __launch_bounds__(256)
gu_kernel(const float* __restrict__ I_seq, const float* __restrict__ t_save,
          const float* __restrict__ U_tau, const float* __restrict__ b_tau,
          const float* __restrict__ U_f,   const float* __restrict__ b_f,
          float* __restrict__ gu)
{
  __shared__ float Ish[NIN];
  const int e = blockIdx.x;
  const int tid = threadIdx.x;
  const int n = e >> 2, s = e & 3;
  const float t0 = t_save[n], t1 = t_save[n + 1];
  const float dt = t1 - t0;
  const float third = 1.0f / 3.0f;
  float t;
  if      (s == 0) t = t0;
  else if (s == 1) t = t0 + dt * third;
  else if (s == 2) t = t0 + (dt * 2.0f) * third;
  else             t = t1;
  const int idx = zoh_index(t);
  Ish[tid] = I_seq[idx * NIN + tid];
  __syncthreads();
  float* go = gu + (size_t)e * 1024;
  #pragma unroll
  for (int m = 0; m < 2; ++m) {
    const float* __restrict__ U = m ? U_f : U_tau;
    const float* __restrict__ b = m ? b_f : b_tau;
    #pragma unroll
    for (int hh = 0; hh < 2; ++hh) {
      const int h = tid + hh * 256;
      const float4* __restrict__ Ur = (const float4*)(U + (size_t)h * NIN);
      float acc = 0.f;
      #pragma unroll 8
      for (int k = 0; k < NIN / 4; ++k) {
        float4 u = Ur[k];
        acc = fmaf(u.x, Ish[4*k+0], acc);
        acc = fmaf(u.y, Ish[4*k+1], acc);
        acc = fmaf(u.z, Ish[4*k+2], acc);
        acc = fmaf(u.w, Ish[4*k+3], acc);
      }
      go[m * 512 + h] = acc + b[h];
    }
  }
}

// Persistent cooperative scan. 16 WGs x 1024 threads.
// Sync is pure dataflow: each state word is a packed (tag<<32 | float bits)
// 8-byte agent-scope atomic. Producer's store IS the release; consumers spin
// on the word until tag==e. No barrier counter, no fences, no vmcnt drains.
// Ping-pong by eval parity; the all-read-all dependency chain guarantees a
// slot is never overwritten (tag e+2) before every consumer has read tag e.
__global__ void __launch_bounds__(NTH, 1)
ltc_main(const float* __restrict__ x0, const float* __restrict__ t_save,
         const float* __restrict__ W_tau, const float* __restrict__ tau0,
         const float* __restrict__ W_f,
         const float* __restrict__ gu,
         unsigned long long* xtag,          // [2][512] packed (tag, value)
         float* __restrict__ out)
{
  const int wg   = blockIdx.x;
  const int tid  = threadIdx.x;
  const int row  = tid >> 4;    // 0..63
  const int seg  = tid & 15;    // 0..15, 32 columns each
  const int base = wg * SLICE;

  const float* wrow = ((row < SLICE)
      ? (W_tau + (size_t)(base + row) * HID)
      : (W_f   + (size_t)(base + row - SLICE) * HID)) + seg * 32;

  float4 w4[8];
  #pragma unroll
  for (int t = 0; t < 8; ++t) w4[t] = ((const float4*)wrow)[t];

  __shared__ float xsp[16 * 36];   // padded stride-36: <=2-way conflicts (free)
  __shared__ float pre[64];

  float y0 = 0.f, k1 = 0.f, k2 = 0.f, k3 = 0.f, curx = 0.f, tz = 0.f;
  if (tid < SLICE) {
    y0   = x0[base + tid];
    curx = y0;
    tz   = tau0[base + tid];
    out[base + tid] = y0;            // out[0] = x0
  }

  for (int n = 0; n < NSTEP; ++n) {
    const float t0 = t_save[n], t1 = t_save[n + 1];
    const float dt = t1 - t0;
    #pragma unroll
    for (int s = 0; s < 4; ++s) {
      const int e = (n << 2) + s;

      // gu loads issued first: latency hides under the spin below
      float gt = 0.f, gf = 0.f;
      if (tid < SLICE) {
        const float* g = gu + (size_t)e * 1024 + base + tid;
        gt = g[0];
        gf = g[512];
      }

      // ---- acquire x_e: spin on packed (tag,value) words, fill LDS ----
      if (tid < HID) {
        float v;
        if (e == 0) {
          v = x0[tid];
        } else {
          const unsigned long long* src = xtag + (size_t)(e & 1) * HID + tid;
          unsigned long long pk;
          do {
            pk = __hip_atomic_load(src, __ATOMIC_RELAXED, __HIP_MEMORY_SCOPE_AGENT);
          } while ((unsigned)(pk >> 32) != (unsigned)e);
          v = __uint_as_float((unsigned)pk);
        }
        xsp[(tid >> 5) * 36 + (tid & 31)] = v;
      }
      __syncthreads();

      // ---- matvec: 32 MACs/thread from VGPR weights + LDS x ----
      float acc = 0.f;
      #pragma unroll
      for (int t = 0; t < 8; ++t) {
        const float4 xv = *reinterpret_cast<const float4*>(&xsp[seg * 36 + 4 * t]);
        acc = fmaf(w4[t].x, xv.x, acc);
        acc = fmaf(w4[t].y, xv.y, acc);
        acc = fmaf(w4[t].z, xv.z, acc);
        acc = fmaf(w4[t].w, xv.w, acc);
      }
      acc += __shfl_xor(acc, 1);
      acc += __shfl_xor(acc, 2);
      acc += __shfl_xor(acc, 4);
      acc += __shfl_xor(acc, 8);
      if ((tid & 15) == 0) pre[row] = acc;
      __syncthreads();

      // ---- elementwise + RK4 update; packed store IS the release ----
      if (tid < SLICE) {
        const float zt  = pre[tid] + gt;
        const float zf  = pre[SLICE + tid] + gf;
        const float ez  = __expf(-fabsf(zt));
        const float sp  = fmaxf(zt, 0.f) + __logf(1.f + ez);
        const float tau = tz + sp;
        const float ef  = __expf(-2.f * fabsf(zf));
        const float th  = (1.f - ef) / (1.f + ef);
        const float f   = (zf >= 0.f) ? th : -th;
        const float d   = f - curx / tau;
        float xnew;
        if      (s == 0) { k1 = d; xnew = y0 + dt * k1 * (1.0f/3.0f); }
        else if (s == 1) { k2 = d; xnew = y0 + dt * (k2 - k1 * (1.0f/3.0f)); }
        else if (s == 2) { k3 = d; xnew = y0 + dt * (k1 - k2 + k3); }
        else {
          xnew = y0 + (k1 + 3.0f * (k2 + k3) + d) * dt * 0.125f;
          y0 = xnew;
          out[(size_t)(n + 1) * HID + base + tid] = xnew;
        }
        curx = xnew;
        const unsigned long long pk =
            ((unsigned long long)(unsigned)(e + 1) << 32) | (unsigned long long)__float_as_uint(xnew);
        __hip_atomic_store(xtag + (size_t)((e + 1) & 1) * HID + base + tid, pk,
                           __ATOMIC_RELAXED, __HIP_MEMORY_SCOPE_AGENT);
      }
      // no trailing syncthreads needed: next eval's LDS fill is ordered by
      // the two syncs above (matvec reads complete before the 2nd sync).
    }
  }
}

extern "C" void kernel_launch(void* const* d_in, const int* in_sizes, int n_in,
                              void* d_out, int out_size, void* d_ws, size_t ws_size,
                              hipStream_t stream) {
  const float* x0     = (const float*)d_in[0];
  const float* I_seq  = (const float*)d_in[1];
  const float* t_save = (const float*)d_in[2];
  const float* W_tau  = (const float*)d_in[3];
  const float* U_tau  = (const float*)d_in[4];
  const float* b_tau  = (const float*)d_in[5];
  const float* tau0   = (const float*)d_in[6];
  const float* W_f    = (const float*)d_in[7];
  const float* U_f    = (const float*)d_in[8];
  const float* b_f    = (const float*)d_in[9];
  float* out = (float*)d_out;

  char* ws = (char*)d_ws;
  unsigned long long* xtag = (unsigned long long*)(ws + 1024);  // [2][512] = 8KB
  float* gu = (float*)(ws + 16384);                             // NEVAL*1024 floats (~16.8 MB)

  // zero the tag words every call -> replay-safe, first-call-safe (tag 0 never matches)
  hipMemsetAsync(xtag, 0, 2 * HID * sizeof(unsigned long long), stream);
  gu_kernel<<<NEVAL, 256, 0, stream>>>(I_seq, t_save, U_tau, b_tau, U_f, b_f, gu);

  void* args[] = { (void*)&x0, (void*)&t_save, (void*)&W_tau, (void*)&tau0, (void*)&W_f,
                   (void*)&gu, (void*)&xtag, (void*)&out };
  hipLaunchCooperativeKernel((const void*)ltc_main, dim3(NWG), dim3(NTH),
                             args, 0, stream);
}